// Round 7
// baseline (566.387 us; speedup 1.0000x reference)
//
#include <hip/hip_runtime.h>

// ---------- bf16 helpers (bit-level, RNE) ----------
__device__ __forceinline__ float bflo(unsigned int u){ return __builtin_bit_cast(float, (unsigned int)(u<<16)); }
__device__ __forceinline__ float bfhi(unsigned int u){ return __builtin_bit_cast(float, (unsigned int)(u & 0xffff0000u)); }
// Raw-hi: treat the full 32-bit word as fp32. Exponent/sign come from the hi
// bf16; low 16 bits act as <=2^-8 relative mantissa noise. Saves the AND.
__device__ __forceinline__ float bfhiraw(unsigned int u){ return __builtin_bit_cast(float, u); }
__device__ __forceinline__ float b2f(unsigned short s){ return __builtin_bit_cast(float, ((unsigned int)s)<<16); }
__device__ __forceinline__ unsigned short f2b(float f){
  unsigned int x = __builtin_bit_cast(unsigned int, f);
  x += 0x7fffu + ((x>>16)&1u);
  return (unsigned short)(x>>16);
}
__device__ __forceinline__ unsigned int packbf(float a, float b){
  return (unsigned int)f2b(a) | ((unsigned int)f2b(b)<<16);
}
__device__ __forceinline__ float dpp_swap1(float s){
  int so = __builtin_amdgcn_mov_dpp(__builtin_bit_cast(int, s), 0xB1, 0xF, 0xF, true); // quad_perm [1,0,3,2]
  return __builtin_bit_cast(float, so);
}

using bf16x8 = __attribute__((ext_vector_type(8))) short;
using f32x4  = __attribute__((ext_vector_type(4))) float;

#define NPOS 65536          // T*H*W
#define SLOT_ELEMS 8388608  // NPOS*128 bf16 elements

// ---------- K0: conv weight fp32 (O,C,3,3) -> bf16 (tap,O,C) ----------
__global__ __launch_bounds__(256) void k_wprep(const float* __restrict__ w1,
                                               const float* __restrict__ w2,
                                               unsigned short* __restrict__ o1,
                                               unsigned short* __restrict__ o2){
  int idx = blockIdx.x*256 + threadIdx.x;
  if (idx >= 147456) return;
  int o = idx / 1152;
  int rem = idx - o*1152;
  int c = rem / 9;
  int tap = rem - c*9;
  int dsti = tap*16384 + o*128 + c;
  o1[dsti] = f2b(w1[idx]);
  o2[dsti] = f2b(w2[idx]);
}

// ---------- K1: LayerNorm over C, fp32 NCHW input -> (N,C) bf16 ----------
__global__ __launch_bounds__(256) void k_ln_nchw(const float* __restrict__ vid,
                                                 const float* __restrict__ g,
                                                 const float* __restrict__ b,
                                                 unsigned short* __restrict__ xf){
  int n = blockIdx.x*256 + threadIdx.x;
  int t = n >> 14, hw = n & 16383;
  const float* base = vid + (size_t)t*2097152 + hw;
  float s=0.f, ss=0.f;
  #pragma unroll 8
  for (int c=0;c<128;c++){ float v=base[(size_t)c*16384]; s+=v; ss+=v*v; }
  float mu  = s*0.0078125f;
  float var = fmaxf(ss*0.0078125f - mu*mu, 0.f);
  float rs  = rsqrtf(var + 1e-6f);
  unsigned int* op = (unsigned int*)(xf + (size_t)n*128);
  #pragma unroll 4
  for (int c=0;c<128;c+=2){
    float v0=(base[(size_t)c*16384]    -mu)*rs*g[c]  +b[c];
    float v1=(base[(size_t)(c+1)*16384]-mu)*rs*g[c+1]+b[c+1];
    op[c>>1]=packbf(v0,v1);
  }
}

// ---------- K5: LayerNorm over C, (N,C) bf16 row-major input ----------
__global__ __launch_bounds__(256) void k_ln_rows(const unsigned short* __restrict__ x,
                                                 const float* __restrict__ g,
                                                 const float* __restrict__ b,
                                                 unsigned short* __restrict__ y){
  int n = blockIdx.x*256 + threadIdx.x;
  const unsigned int* p = (const unsigned int*)(x + (size_t)n*128);
  float s=0.f, ss=0.f;
  #pragma unroll 8
  for (int j=0;j<64;j++){ unsigned int u=p[j]; float v0=bflo(u),v1=bfhi(u); s+=v0+v1; ss+=v0*v0+v1*v1; }
  float mu  = s*0.0078125f;
  float var = fmaxf(ss*0.0078125f - mu*mu, 0.f);
  float rs  = rsqrtf(var + 1e-6f);
  unsigned int* op=(unsigned int*)(y+(size_t)n*128);
  #pragma unroll 8
  for (int j=0;j<64;j++){
    unsigned int u=p[j];
    float v0=(bflo(u)-mu)*rs*g[2*j]  +b[2*j];
    float v1=(bfhi(u)-mu)*rs*g[2*j+1]+b[2*j+1];
    op[j]=packbf(v0,v1);
  }
}

// ---------- K2: QKV projections. qf may alias xf (in-place, own wave-band) ----------
// NOTE: xf/qf intentionally NOT __restrict__ (qf may alias xf).
__global__ __launch_bounds__(256) void k_qkv(const unsigned short* xf,
                                             const float* __restrict__ Wq,
                                             const float* __restrict__ Wk,
                                             const float* __restrict__ Wv,
                                             unsigned short* qf,
                                             unsigned short* __restrict__ kfo,
                                             unsigned short* __restrict__ vfo){
  __shared__ unsigned short wlds[16384];
  int wave = threadIdx.x>>6, lane = threadIdx.x&63;
  int m0 = blockIdx.x*64 + wave*16;
  int mrow = lane&15, quad = lane>>4;
  bf16x8 a[4];
  const unsigned short* ap = xf + (size_t)(m0+mrow)*128 + quad*8;
  #pragma unroll
  for (int kc=0;kc<4;kc++) a[kc] = *(const bf16x8*)(ap + kc*32);
  const float* Ws[3] = {Wq, Wk, Wv};
  unsigned short* outs[3] = {qf, kfo, vfo};
  for (int mat=0; mat<3; mat++){
    __syncthreads();
    { const float2* src=(const float2*)Ws[mat]; unsigned int* dst=(unsigned int*)wlds;
      for (int i=threadIdx.x;i<8192;i+=256){ float2 wv=src[i]; dst[i]=packbf(wv.x,wv.y); } }
    __syncthreads();
    unsigned short* out = outs[mat];
    for (int nt=0;nt<8;nt++){
      f32x4 acc = {0.f,0.f,0.f,0.f};
      #pragma unroll
      for (int kc=0;kc<4;kc++){
        bf16x8 bfr = *(const bf16x8*)(wlds + (nt*16+mrow)*128 + kc*32 + quad*8);
        acc = __builtin_amdgcn_mfma_f32_16x16x32_bf16(a[kc], bfr, acc, 0,0,0);
      }
      int col = nt*16+mrow;
      unsigned short* op = out + (size_t)(m0 + quad*4)*128 + col;
      #pragma unroll
      for (int r=0;r<4;r++) op[(size_t)r*128] = f2b(acc[r]);
    }
  }
}

// ---------- K3: space-time neighborhood attention, channel-split, lean inner loop ----------
// XCD-banded: xcd = blockIdx%8 owns rows h in [xcd*16, xcd*16+16) (all 4 frames).
// Thread = (w, head, cpart): cpart owns 16 of the head's 32 channels for all 147
// offsets. Dot partials combined per-offset via DPP pair-swap (VALU-only).
// K/V unpack uses raw-hi trick (no AND); loads use uniform-base + 32-bit voffset.
__global__ __launch_bounds__(256) void k_attn(const unsigned short* qf,
                                              const unsigned short* __restrict__ kf,
                                              const unsigned short* __restrict__ vf,
                                              const float* __restrict__ flw,
                                              unsigned short* attf){
  int xcd = blockIdx.x & 7;
  int j   = blockIdx.x >> 3;      // 0..255
  int t       = j >> 6;           // 0..3
  int r       = j & 63;
  int h_local = r >> 2;           // 0..15
  int wq      = r & 3;            // 0..3
  int h = xcd*16 + h_local;
  int w = wq*32 + (threadIdx.x >> 3);
  int head  = (threadIdx.x >> 1) & 3;
  int cpart = threadIdx.x & 1;
  int hw = (h<<7) + w;
  int n  = (t<<14) + hw;
  float fh = flw[t*32768 + hw];
  float fw = flw[t*32768 + 16384 + hw];
  unsigned coff = head*32 + cpart*16;     // this thread's 16-channel slice
  const uint4* qp = (const uint4*)(qf + (size_t)n*128 + coff);
  float q[16];
  #pragma unroll
  for (int i=0;i<2;i++){
    uint4 qv = qp[i];
    q[8*i+0]=bflo(qv.x); q[8*i+1]=bfhi(qv.x);
    q[8*i+2]=bflo(qv.y); q[8*i+3]=bfhi(qv.y);
    q[8*i+4]=bflo(qv.z); q[8*i+5]=bfhi(qv.z);
    q[8*i+6]=bflo(qv.w); q[8*i+7]=bfhi(qv.w);
  }
  float acc[16];
  #pragma unroll
  for (int i=0;i<16;i++) acc[i]=0.f;
  float l = 0.f;
  #pragma unroll 1
  for (int dt=-1; dt<=1; dt++){
    int ti = t+dt; ti = ti<0?0:(ti>3?3:ti);
    int oh = (int)rintf(fh*(float)dt);   // round-half-even matches jnp.round
    int ow = (int)rintf(fw*(float)dt);
    int hb = h+oh, wb = w+ow;
    #pragma unroll 1
    for (int dh=-3; dh<=3; dh++){
      int hi = hb+dh; hi = hi<0?0:(hi>127?127:hi);
      int rb = (ti<<14)+(hi<<7);
      #pragma unroll 1
      for (int dw=-3; dw<=3; dw++){
        int wi = wb+dw; wi = wi<0?0:(wi>127?127:wi);
        unsigned boff = ((unsigned)(rb+wi)<<7) + coff;   // element offset, 32-bit
        const uint4* kp = (const uint4*)(kf + boff);
        uint4 k0=kp[0], k1=kp[1];
        const uint4* vp = (const uint4*)(vf + boff);
        uint4 v0=vp[0], v1=vp[1];
        float s = 0.f;
        s += q[0]*bflo(k0.x) + q[1]*bfhiraw(k0.x);
        s += q[2]*bflo(k0.y) + q[3]*bfhiraw(k0.y);
        s += q[4]*bflo(k0.z) + q[5]*bfhiraw(k0.z);
        s += q[6]*bflo(k0.w) + q[7]*bfhiraw(k0.w);
        s += q[8]*bflo(k1.x) + q[9]*bfhiraw(k1.x);
        s += q[10]*bflo(k1.y) + q[11]*bfhiraw(k1.y);
        s += q[12]*bflo(k1.z) + q[13]*bfhiraw(k1.z);
        s += q[14]*bflo(k1.w) + q[15]*bfhiraw(k1.w);
        s += dpp_swap1(s);               // combine the two channel halves
        float e = __expf(s * 0.17677669529663687f);
        l += e;
        acc[0]  += e*bflo(v0.x); acc[1]  += e*bfhiraw(v0.x);
        acc[2]  += e*bflo(v0.y); acc[3]  += e*bfhiraw(v0.y);
        acc[4]  += e*bflo(v0.z); acc[5]  += e*bfhiraw(v0.z);
        acc[6]  += e*bflo(v0.w); acc[7]  += e*bfhiraw(v0.w);
        acc[8]  += e*bflo(v1.x); acc[9]  += e*bfhiraw(v1.x);
        acc[10] += e*bflo(v1.y); acc[11] += e*bfhiraw(v1.y);
        acc[12] += e*bflo(v1.z); acc[13] += e*bfhiraw(v1.z);
        acc[14] += e*bflo(v1.w); acc[15] += e*bfhiraw(v1.w);
      }
    }
  }
  float inv = 1.f/l;
  unsigned int* op = (unsigned int*)(attf + (size_t)n*128 + coff);
  #pragma unroll
  for (int i=0;i<8;i++) op[i]=packbf(acc[2*i]*inv, acc[2*i+1]*inv);
}

// ---------- K4: Wo projection + residual (vid fp32 NCHW). vid1 may alias attf ----------
__global__ __launch_bounds__(256) void k_wo(const unsigned short* attf,
                                            const float* __restrict__ Wo,
                                            const float* __restrict__ vid,
                                            unsigned short* vid1){
  __shared__ unsigned short wlds[16384];
  int wave = threadIdx.x>>6, lane = threadIdx.x&63;
  int m0 = blockIdx.x*64 + wave*16;
  int mrow = lane&15, quad = lane>>4;
  bf16x8 a[4];
  const unsigned short* ap = attf + (size_t)(m0+mrow)*128 + quad*8;
  #pragma unroll
  for (int kc=0;kc<4;kc++) a[kc] = *(const bf16x8*)(ap + kc*32);
  { const float2* src=(const float2*)Wo; unsigned int* dst=(unsigned int*)wlds;
    for (int i=threadIdx.x;i<8192;i+=256){ float2 wv=src[i]; dst[i]=packbf(wv.x,wv.y); } }
  __syncthreads();
  for (int nt=0;nt<8;nt++){
    f32x4 acc={0.f,0.f,0.f,0.f};
    #pragma unroll
    for (int kc=0;kc<4;kc++){
      bf16x8 bfr = *(const bf16x8*)(wlds + (nt*16+mrow)*128 + kc*32 + quad*8);
      acc = __builtin_amdgcn_mfma_f32_16x16x32_bf16(a[kc], bfr, acc, 0,0,0);
    }
    int col = nt*16+mrow;
    #pragma unroll
    for (int r=0;r<4;r++){
      int nrow = m0 + quad*4 + r;
      int tt = nrow>>14, hww = nrow&16383;
      float resid = vid[(size_t)tt*2097152 + (size_t)col*16384 + hww];
      vid1[(size_t)nrow*128 + col] = f2b(resid + acc[r]);
    }
  }
}

// ---------- K6: 3x3 conv (9-tap MFMA GEMM) + bias + tanh-GELU ----------
__global__ __launch_bounds__(256) void k_conv_gelu(const unsigned short* __restrict__ src,
                                                   const unsigned short* __restrict__ wtap,
                                                   const float* __restrict__ bias,
                                                   unsigned short* __restrict__ dst){
  __shared__ unsigned short wlds[16384];
  int wave=threadIdx.x>>6, lane=threadIdx.x&63;
  int frame=blockIdx.x>>8, tile=blockIdx.x&255;
  int m0=tile*64+wave*16;
  int mrow=lane&15, quad=lane>>4;
  int p=m0+mrow, h=p>>7, w=p&127;
  size_t nf=(size_t)frame*16384;
  f32x4 acc[8];
  #pragma unroll
  for (int i=0;i<8;i++) acc[i]=(f32x4){0.f,0.f,0.f,0.f};
  for (int tap=0;tap<9;tap++){
    __syncthreads();
    { const uint4* s4=(const uint4*)(wtap + (size_t)tap*16384);
      uint4* d4=(uint4*)wlds;
      for (int i=threadIdx.x;i<2048;i+=256) d4[i]=s4[i]; }
    __syncthreads();
    int ky=tap/3, kx=tap-3*ky;
    int h2=h+ky-1, w2=w+kx-1;
    bf16x8 a[4];
    if ((unsigned)h2<128u && (unsigned)w2<128u){
      const unsigned short* ap = src + (nf + (size_t)(h2*128+w2))*128 + quad*8;
      #pragma unroll
      for (int kc=0;kc<4;kc++) a[kc]=*(const bf16x8*)(ap+kc*32);
    } else {
      #pragma unroll
      for (int kc=0;kc<4;kc++) a[kc]=(bf16x8){0,0,0,0,0,0,0,0};
    }
    for (int nt=0;nt<8;nt++){
      #pragma unroll
      for (int kc=0;kc<4;kc++){
        bf16x8 bfr=*(const bf16x8*)(wlds + (nt*16+mrow)*128 + kc*32 + quad*8);
        acc[nt]=__builtin_amdgcn_mfma_f32_16x16x32_bf16(a[kc],bfr,acc[nt],0,0,0);
      }
    }
  }
  #pragma unroll
  for (int nt=0;nt<8;nt++){
    int col=nt*16+mrow;
    float bb=bias[col];
    #pragma unroll
    for (int r=0;r<4;r++){
      int pr=m0+quad*4+r;
      float x=acc[nt][r]+bb;
      // tanh-GELU via sigmoid: 0.5x(1+tanh(z)) = x * 1/(1+exp(-2z))
      float z = 0.7978845608028654f*(x+0.044715f*x*x*x);
      float gl = x * __builtin_amdgcn_rcpf(1.f + __expf(-2.f*z));
      dst[(nf+(size_t)pr)*128+col]=f2b(gl);
    }
  }
}

// ---------- K7: 3x3 conv + bias + (vid1 + yb + r) -> d_out fp32 NCHW ----------
__global__ __launch_bounds__(256) void k_conv_final(const unsigned short* __restrict__ src,
                                                    const unsigned short* __restrict__ wtap,
                                                    const float* __restrict__ bias,
                                                    const unsigned short* __restrict__ yb,
                                                    const unsigned short* __restrict__ vid1,
                                                    float* __restrict__ out){
  __shared__ unsigned short wlds[16384];
  int wave=threadIdx.x>>6, lane=threadIdx.x&63;
  int frame=blockIdx.x>>8, tile=blockIdx.x&255;
  int m0=tile*64+wave*16;
  int mrow=lane&15, quad=lane>>4;
  int p=m0+mrow, h=p>>7, w=p&127;
  size_t nf=(size_t)frame*16384;
  f32x4 acc[8];
  #pragma unroll
  for (int i=0;i<8;i++) acc[i]=(f32x4){0.f,0.f,0.f,0.f};
  for (int tap=0;tap<9;tap++){
    __syncthreads();
    { const uint4* s4=(const uint4*)(wtap + (size_t)tap*16384);
      uint4* d4=(uint4*)wlds;
      for (int i=threadIdx.x;i<2048;i+=256) d4[i]=s4[i]; }
    __syncthreads();
    int ky=tap/3, kx=tap-3*ky;
    int h2=h+ky-1, w2=w+kx-1;
    bf16x8 a[4];
    if ((unsigned)h2<128u && (unsigned)w2<128u){
      const unsigned short* ap = src + (nf + (size_t)(h2*128+w2))*128 + quad*8;
      #pragma unroll
      for (int kc=0;kc<4;kc++) a[kc]=*(const bf16x8*)(ap+kc*32);
    } else {
      #pragma unroll
      for (int kc=0;kc<4;kc++) a[kc]=(bf16x8){0,0,0,0,0,0,0,0};
    }
    for (int nt=0;nt<8;nt++){
      #pragma unroll
      for (int kc=0;kc<4;kc++){
        bf16x8 bfr=*(const bf16x8*)(wlds + (nt*16+mrow)*128 + kc*32 + quad*8);
        acc[nt]=__builtin_amdgcn_mfma_f32_16x16x32_bf16(a[kc],bfr,acc[nt],0,0,0);
      }
    }
  }
  #pragma unroll
  for (int nt=0;nt<8;nt++){
    int col=nt*16+mrow;
    float bb=bias[col];
    #pragma unroll
    for (int r=0;r<4;r++){
      int pr=m0+quad*4+r;
      size_t nrow=nf+(size_t)pr;
      float x=acc[nt][r]+bb;
      float v1=b2f(vid1[nrow*128+col]);
      float yv=b2f(yb[nrow*128+col]);
      out[(size_t)frame*2097152 + (size_t)col*16384 + pr]=v1+yv+x;
    }
  }
}

extern "C" void kernel_launch(void* const* d_in, const int* in_sizes, int n_in,
                              void* d_out, int out_size, void* d_ws, size_t ws_size,
                              hipStream_t stream) {
  const float* vid  = (const float*)d_in[0];
  const float* flw  = (const float*)d_in[1];
  const float* g0   = (const float*)d_in[2];
  const float* b0   = (const float*)d_in[3];
  const float* Wq   = (const float*)d_in[4];
  const float* Wk   = (const float*)d_in[5];
  const float* Wv   = (const float*)d_in[6];
  const float* Wo   = (const float*)d_in[7];
  const float* g1   = (const float*)d_in[8];
  const float* b1   = (const float*)d_in[9];
  const float* wr1  = (const float*)d_in[10];
  const float* br1  = (const float*)d_in[11];
  const float* wr2  = (const float*)d_in[12];
  const float* br2  = (const float*)d_in[13];
  float* out = (float*)d_out;

  unsigned short* A  = (unsigned short*)d_ws;
  unsigned short* Bs = A + SLOT_ELEMS;
  unsigned short* Cs = Bs + SLOT_ELEMS;
  bool four = ws_size >= (size_t)4*SLOT_ELEMS*2 + 2*294912;
  unsigned short* D  = four ? (Cs + SLOT_ELEMS) : A;   // q/att/vid1 slot
  unsigned short* wt1 = Cs + SLOT_ELEMS + (four ? SLOT_ELEMS : 0);
  unsigned short* wt2 = wt1 + 147456;

  k_wprep   <<<576, 256, 0, stream>>>(wr1, wr2, wt1, wt2);
  k_ln_nchw <<<256, 256, 0, stream>>>(vid, g0, b0, A);
  k_qkv     <<<1024,256, 0, stream>>>(A, Wq, Wk, Wv, D, Bs, Cs);
  k_attn    <<<2048,256, 0, stream>>>(D, Bs, Cs, flw, D);
  k_wo      <<<1024,256, 0, stream>>>(D, Wo, vid, D);
  k_ln_rows <<<256, 256, 0, stream>>>(D, g1, b1, Bs);
  k_conv_gelu <<<1024,256,0, stream>>>(Bs, wt1, br1, Cs);
  k_conv_final<<<1024,256,0, stream>>>(Cs, wt2, br2, Bs, D, out);
}

// Round 8
// 511.098 us; speedup vs baseline: 1.1082x; 1.1082x over previous
//
#include <hip/hip_runtime.h>

// ---------- bf16 helpers (bit-level, RNE) ----------
__device__ __forceinline__ float bflo(unsigned int u){ return __builtin_bit_cast(float, (unsigned int)(u<<16)); }
__device__ __forceinline__ float bfhi(unsigned int u){ return __builtin_bit_cast(float, (unsigned int)(u & 0xffff0000u)); }
// Raw-hi: treat the full 32-bit word as fp32. Exponent/sign come from the hi
// bf16; low 16 bits act as <=2^-8 relative mantissa noise. Saves the AND.
__device__ __forceinline__ float bfhiraw(unsigned int u){ return __builtin_bit_cast(float, u); }
__device__ __forceinline__ float b2f(unsigned short s){ return __builtin_bit_cast(float, ((unsigned int)s)<<16); }
__device__ __forceinline__ unsigned short f2b(float f){
  unsigned int x = __builtin_bit_cast(unsigned int, f);
  x += 0x7fffu + ((x>>16)&1u);
  return (unsigned short)(x>>16);
}
__device__ __forceinline__ unsigned int packbf(float a, float b){
  return (unsigned int)f2b(a) | ((unsigned int)f2b(b)<<16);
}
__device__ __forceinline__ float dpp_swap1(float s){
  int so = __builtin_amdgcn_mov_dpp(__builtin_bit_cast(int, s), 0xB1, 0xF, 0xF, true); // quad_perm [1,0,3,2]
  return __builtin_bit_cast(float, so);
}

using bf16x8 = __attribute__((ext_vector_type(8))) short;
using f32x4  = __attribute__((ext_vector_type(4))) float;

#define NPOS 65536          // T*H*W
#define SLOT_ELEMS 8388608  // NPOS*128 bf16 elements

// ---------- K0: conv weight fp32 (O,C,3,3) -> bf16 (tap,O,C) ----------
__global__ __launch_bounds__(256) void k_wprep(const float* __restrict__ w1,
                                               const float* __restrict__ w2,
                                               unsigned short* __restrict__ o1,
                                               unsigned short* __restrict__ o2){
  int idx = blockIdx.x*256 + threadIdx.x;
  if (idx >= 147456) return;
  int o = idx / 1152;
  int rem = idx - o*1152;
  int c = rem / 9;
  int tap = rem - c*9;
  int dsti = tap*16384 + o*128 + c;
  o1[dsti] = f2b(w1[idx]);
  o2[dsti] = f2b(w2[idx]);
}

// ---------- K1: LayerNorm over C, fp32 NCHW input -> (N,C) bf16 ----------
__global__ __launch_bounds__(256) void k_ln_nchw(const float* __restrict__ vid,
                                                 const float* __restrict__ g,
                                                 const float* __restrict__ b,
                                                 unsigned short* __restrict__ xf){
  int n = blockIdx.x*256 + threadIdx.x;
  int t = n >> 14, hw = n & 16383;
  const float* base = vid + (size_t)t*2097152 + hw;
  float s=0.f, ss=0.f;
  #pragma unroll 8
  for (int c=0;c<128;c++){ float v=base[(size_t)c*16384]; s+=v; ss+=v*v; }
  float mu  = s*0.0078125f;
  float var = fmaxf(ss*0.0078125f - mu*mu, 0.f);
  float rs  = rsqrtf(var + 1e-6f);
  unsigned int* op = (unsigned int*)(xf + (size_t)n*128);
  #pragma unroll 4
  for (int c=0;c<128;c+=2){
    float v0=(base[(size_t)c*16384]    -mu)*rs*g[c]  +b[c];
    float v1=(base[(size_t)(c+1)*16384]-mu)*rs*g[c+1]+b[c+1];
    op[c>>1]=packbf(v0,v1);
  }
}

// ---------- K5: LayerNorm over C, (N,C) bf16 row-major input ----------
__global__ __launch_bounds__(256) void k_ln_rows(const unsigned short* __restrict__ x,
                                                 const float* __restrict__ g,
                                                 const float* __restrict__ b,
                                                 unsigned short* __restrict__ y){
  int n = blockIdx.x*256 + threadIdx.x;
  const unsigned int* p = (const unsigned int*)(x + (size_t)n*128);
  float s=0.f, ss=0.f;
  #pragma unroll 8
  for (int j=0;j<64;j++){ unsigned int u=p[j]; float v0=bflo(u),v1=bfhi(u); s+=v0+v1; ss+=v0*v0+v1*v1; }
  float mu  = s*0.0078125f;
  float var = fmaxf(ss*0.0078125f - mu*mu, 0.f);
  float rs  = rsqrtf(var + 1e-6f);
  unsigned int* op=(unsigned int*)(y+(size_t)n*128);
  #pragma unroll 8
  for (int j=0;j<64;j++){
    unsigned int u=p[j];
    float v0=(bflo(u)-mu)*rs*g[2*j]  +b[2*j];
    float v1=(bfhi(u)-mu)*rs*g[2*j+1]+b[2*j+1];
    op[j]=packbf(v0,v1);
  }
}

// ---------- K2: QKV projections. qf may alias xf (in-place, own wave-band) ----------
// NOTE: xf/qf intentionally NOT __restrict__ (qf may alias xf).
__global__ __launch_bounds__(256) void k_qkv(const unsigned short* xf,
                                             const float* __restrict__ Wq,
                                             const float* __restrict__ Wk,
                                             const float* __restrict__ Wv,
                                             unsigned short* qf,
                                             unsigned short* __restrict__ kfo,
                                             unsigned short* __restrict__ vfo){
  __shared__ unsigned short wlds[16384];
  int wave = threadIdx.x>>6, lane = threadIdx.x&63;
  int m0 = blockIdx.x*64 + wave*16;
  int mrow = lane&15, quad = lane>>4;
  bf16x8 a[4];
  const unsigned short* ap = xf + (size_t)(m0+mrow)*128 + quad*8;
  #pragma unroll
  for (int kc=0;kc<4;kc++) a[kc] = *(const bf16x8*)(ap + kc*32);
  const float* Ws[3] = {Wq, Wk, Wv};
  unsigned short* outs[3] = {qf, kfo, vfo};
  for (int mat=0; mat<3; mat++){
    __syncthreads();
    { const float2* src=(const float2*)Ws[mat]; unsigned int* dst=(unsigned int*)wlds;
      for (int i=threadIdx.x;i<8192;i+=256){ float2 wv=src[i]; dst[i]=packbf(wv.x,wv.y); } }
    __syncthreads();
    unsigned short* out = outs[mat];
    for (int nt=0;nt<8;nt++){
      f32x4 acc = {0.f,0.f,0.f,0.f};
      #pragma unroll
      for (int kc=0;kc<4;kc++){
        bf16x8 bfr = *(const bf16x8*)(wlds + (nt*16+mrow)*128 + kc*32 + quad*8);
        acc = __builtin_amdgcn_mfma_f32_16x16x32_bf16(a[kc], bfr, acc, 0,0,0);
      }
      int col = nt*16+mrow;
      unsigned short* op = out + (size_t)(m0 + quad*4)*128 + col;
      #pragma unroll
      for (int r=0;r<4;r++) op[(size_t)r*128] = f2b(acc[r]);
    }
  }
}

// ---------- K3: space-time neighborhood attention, channel-split, dw-pipelined ----------
// XCD-banded: xcd = blockIdx%8 owns rows h in [xcd*16, xcd*16+16) (all 4 frames).
// Thread = (w, head, cpart): cpart owns 16 of the head's 32 channels for all 147
// offsets; DPP pair-swap combines the dot halves. The dw loop (7 iters) is fully
// unrolled with a depth-1 software pipeline: offset i+1's K/V loads issue before
// offset i's dependent chain (dot->exp->acc), hiding L1-hit latency.
__global__ __launch_bounds__(256) void k_attn(const unsigned short* qf,
                                              const unsigned short* __restrict__ kf,
                                              const unsigned short* __restrict__ vf,
                                              const float* __restrict__ flw,
                                              unsigned short* attf){
  int xcd = blockIdx.x & 7;
  int j   = blockIdx.x >> 3;      // 0..255
  int t       = j >> 6;           // 0..3
  int r       = j & 63;
  int h_local = r >> 2;           // 0..15
  int wq      = r & 3;            // 0..3
  int h = xcd*16 + h_local;
  int w = wq*32 + (threadIdx.x >> 3);
  int head  = (threadIdx.x >> 1) & 3;
  int cpart = threadIdx.x & 1;
  int hw = (h<<7) + w;
  int n  = (t<<14) + hw;
  float fh = flw[t*32768 + hw];
  float fw = flw[t*32768 + 16384 + hw];
  unsigned coff = head*32 + cpart*16;     // this thread's 16-channel slice
  const uint4* qp = (const uint4*)(qf + (size_t)n*128 + coff);
  float q[16];
  #pragma unroll
  for (int i=0;i<2;i++){
    uint4 qv = qp[i];
    q[8*i+0]=bflo(qv.x); q[8*i+1]=bfhi(qv.x);
    q[8*i+2]=bflo(qv.y); q[8*i+3]=bfhi(qv.y);
    q[8*i+4]=bflo(qv.z); q[8*i+5]=bfhi(qv.z);
    q[8*i+6]=bflo(qv.w); q[8*i+7]=bfhi(qv.w);
  }
  float acc[16];
  #pragma unroll
  for (int i=0;i<16;i++) acc[i]=0.f;
  float l = 0.f;
  #pragma unroll 1
  for (int dt=-1; dt<=1; dt++){
    int ti = t+dt; ti = ti<0?0:(ti>3?3:ti);
    int oh = (int)rintf(fh*(float)dt);   // round-half-even matches jnp.round
    int ow = (int)rintf(fw*(float)dt);
    int hb = h+oh, wb = w+ow;
    #pragma unroll 1
    for (int dh=-3; dh<=3; dh++){
      int hi = hb+dh; hi = hi<0?0:(hi>127?127:hi);
      int rb = (ti<<14)+(hi<<7);
      unsigned bo[7];
      #pragma unroll
      for (int i=0;i<7;i++){
        int wi = wb-3+i; wi = wi<0?0:(wi>127?127:wi);
        bo[i] = ((unsigned)(rb+wi)<<7) + coff;
      }
      // prologue: load offset 0
      uint4 ka0 = ((const uint4*)(kf + bo[0]))[0];
      uint4 ka1 = ((const uint4*)(kf + bo[0]))[1];
      uint4 va0 = ((const uint4*)(vf + bo[0]))[0];
      uint4 va1 = ((const uint4*)(vf + bo[0]))[1];
      #pragma unroll
      for (int i=0;i<7;i++){
        uint4 kb0, kb1, vb0, vb1;
        if (i<6){
          kb0 = ((const uint4*)(kf + bo[i+1]))[0];
          kb1 = ((const uint4*)(kf + bo[i+1]))[1];
          vb0 = ((const uint4*)(vf + bo[i+1]))[0];
          vb1 = ((const uint4*)(vf + bo[i+1]))[1];
        }
        float s = 0.f;
        s += q[0]*bflo(ka0.x) + q[1]*bfhiraw(ka0.x);
        s += q[2]*bflo(ka0.y) + q[3]*bfhiraw(ka0.y);
        s += q[4]*bflo(ka0.z) + q[5]*bfhiraw(ka0.z);
        s += q[6]*bflo(ka0.w) + q[7]*bfhiraw(ka0.w);
        s += q[8]*bflo(ka1.x) + q[9]*bfhiraw(ka1.x);
        s += q[10]*bflo(ka1.y) + q[11]*bfhiraw(ka1.y);
        s += q[12]*bflo(ka1.z) + q[13]*bfhiraw(ka1.z);
        s += q[14]*bflo(ka1.w) + q[15]*bfhiraw(ka1.w);
        s += dpp_swap1(s);               // combine the two channel halves
        float e = __expf(s * 0.17677669529663687f);
        l += e;
        acc[0]  += e*bflo(va0.x); acc[1]  += e*bfhiraw(va0.x);
        acc[2]  += e*bflo(va0.y); acc[3]  += e*bfhiraw(va0.y);
        acc[4]  += e*bflo(va0.z); acc[5]  += e*bfhiraw(va0.z);
        acc[6]  += e*bflo(va0.w); acc[7]  += e*bfhiraw(va0.w);
        acc[8]  += e*bflo(va1.x); acc[9]  += e*bfhiraw(va1.x);
        acc[10] += e*bflo(va1.y); acc[11] += e*bfhiraw(va1.y);
        acc[12] += e*bflo(va1.z); acc[13] += e*bfhiraw(va1.z);
        acc[14] += e*bflo(va1.w); acc[15] += e*bfhiraw(va1.w);
        ka0=kb0; ka1=kb1; va0=vb0; va1=vb1;
      }
    }
  }
  float inv = 1.f/l;
  unsigned int* op = (unsigned int*)(attf + (size_t)n*128 + coff);
  #pragma unroll
  for (int i=0;i<8;i++) op[i]=packbf(acc[2*i]*inv, acc[2*i+1]*inv);
}

// ---------- K4: Wo projection + residual (vid fp32 NCHW). vid1 may alias attf ----------
__global__ __launch_bounds__(256) void k_wo(const unsigned short* attf,
                                            const float* __restrict__ Wo,
                                            const float* __restrict__ vid,
                                            unsigned short* vid1){
  __shared__ unsigned short wlds[16384];
  int wave = threadIdx.x>>6, lane = threadIdx.x&63;
  int m0 = blockIdx.x*64 + wave*16;
  int mrow = lane&15, quad = lane>>4;
  bf16x8 a[4];
  const unsigned short* ap = attf + (size_t)(m0+mrow)*128 + quad*8;
  #pragma unroll
  for (int kc=0;kc<4;kc++) a[kc] = *(const bf16x8*)(ap + kc*32);
  { const float2* src=(const float2*)Wo; unsigned int* dst=(unsigned int*)wlds;
    for (int i=threadIdx.x;i<8192;i+=256){ float2 wv=src[i]; dst[i]=packbf(wv.x,wv.y); } }
  __syncthreads();
  for (int nt=0;nt<8;nt++){
    f32x4 acc={0.f,0.f,0.f,0.f};
    #pragma unroll
    for (int kc=0;kc<4;kc++){
      bf16x8 bfr = *(const bf16x8*)(wlds + (nt*16+mrow)*128 + kc*32 + quad*8);
      acc = __builtin_amdgcn_mfma_f32_16x16x32_bf16(a[kc], bfr, acc, 0,0,0);
    }
    int col = nt*16+mrow;
    #pragma unroll
    for (int r=0;r<4;r++){
      int nrow = m0 + quad*4 + r;
      int tt = nrow>>14, hww = nrow&16383;
      float resid = vid[(size_t)tt*2097152 + (size_t)col*16384 + hww];
      vid1[(size_t)nrow*128 + col] = f2b(resid + acc[r]);
    }
  }
}

// ---------- K6: 3x3 conv (9-tap MFMA GEMM) + bias + tanh-GELU ----------
__global__ __launch_bounds__(256) void k_conv_gelu(const unsigned short* __restrict__ src,
                                                   const unsigned short* __restrict__ wtap,
                                                   const float* __restrict__ bias,
                                                   unsigned short* __restrict__ dst){
  __shared__ unsigned short wlds[16384];
  int wave=threadIdx.x>>6, lane=threadIdx.x&63;
  int frame=blockIdx.x>>8, tile=blockIdx.x&255;
  int m0=tile*64+wave*16;
  int mrow=lane&15, quad=lane>>4;
  int p=m0+mrow, h=p>>7, w=p&127;
  size_t nf=(size_t)frame*16384;
  f32x4 acc[8];
  #pragma unroll
  for (int i=0;i<8;i++) acc[i]=(f32x4){0.f,0.f,0.f,0.f};
  for (int tap=0;tap<9;tap++){
    __syncthreads();
    { const uint4* s4=(const uint4*)(wtap + (size_t)tap*16384);
      uint4* d4=(uint4*)wlds;
      for (int i=threadIdx.x;i<2048;i+=256) d4[i]=s4[i]; }
    __syncthreads();
    int ky=tap/3, kx=tap-3*ky;
    int h2=h+ky-1, w2=w+kx-1;
    bf16x8 a[4];
    if ((unsigned)h2<128u && (unsigned)w2<128u){
      const unsigned short* ap = src + (nf + (size_t)(h2*128+w2))*128 + quad*8;
      #pragma unroll
      for (int kc=0;kc<4;kc++) a[kc]=*(const bf16x8*)(ap+kc*32);
    } else {
      #pragma unroll
      for (int kc=0;kc<4;kc++) a[kc]=(bf16x8){0,0,0,0,0,0,0,0};
    }
    for (int nt=0;nt<8;nt++){
      #pragma unroll
      for (int kc=0;kc<4;kc++){
        bf16x8 bfr=*(const bf16x8*)(wlds + (nt*16+mrow)*128 + kc*32 + quad*8);
        acc[nt]=__builtin_amdgcn_mfma_f32_16x16x32_bf16(a[kc],bfr,acc[nt],0,0,0);
      }
    }
  }
  #pragma unroll
  for (int nt=0;nt<8;nt++){
    int col=nt*16+mrow;
    float bb=bias[col];
    #pragma unroll
    for (int r=0;r<4;r++){
      int pr=m0+quad*4+r;
      float x=acc[nt][r]+bb;
      // tanh-GELU via sigmoid: 0.5x(1+tanh(z)) = x * 1/(1+exp(-2z))
      float z = 0.7978845608028654f*(x+0.044715f*x*x*x);
      float gl = x * __builtin_amdgcn_rcpf(1.f + __expf(-2.f*z));
      dst[(nf+(size_t)pr)*128+col]=f2b(gl);
    }
  }
}

// ---------- K7: 3x3 conv + bias + (vid1 + yb + r) -> d_out fp32 NCHW ----------
__global__ __launch_bounds__(256) void k_conv_final(const unsigned short* __restrict__ src,
                                                    const unsigned short* __restrict__ wtap,
                                                    const float* __restrict__ bias,
                                                    const unsigned short* __restrict__ yb,
                                                    const unsigned short* __restrict__ vid1,
                                                    float* __restrict__ out){
  __shared__ unsigned short wlds[16384];
  int wave=threadIdx.x>>6, lane=threadIdx.x&63;
  int frame=blockIdx.x>>8, tile=blockIdx.x&255;
  int m0=tile*64+wave*16;
  int mrow=lane&15, quad=lane>>4;
  int p=m0+mrow, h=p>>7, w=p&127;
  size_t nf=(size_t)frame*16384;
  f32x4 acc[8];
  #pragma unroll
  for (int i=0;i<8;i++) acc[i]=(f32x4){0.f,0.f,0.f,0.f};
  for (int tap=0;tap<9;tap++){
    __syncthreads();
    { const uint4* s4=(const uint4*)(wtap + (size_t)tap*16384);
      uint4* d4=(uint4*)wlds;
      for (int i=threadIdx.x;i<2048;i+=256) d4[i]=s4[i]; }
    __syncthreads();
    int ky=tap/3, kx=tap-3*ky;
    int h2=h+ky-1, w2=w+kx-1;
    bf16x8 a[4];
    if ((unsigned)h2<128u && (unsigned)w2<128u){
      const unsigned short* ap = src + (nf + (size_t)(h2*128+w2))*128 + quad*8;
      #pragma unroll
      for (int kc=0;kc<4;kc++) a[kc]=*(const bf16x8*)(ap+kc*32);
    } else {
      #pragma unroll
      for (int kc=0;kc<4;kc++) a[kc]=(bf16x8){0,0,0,0,0,0,0,0};
    }
    for (int nt=0;nt<8;nt++){
      #pragma unroll
      for (int kc=0;kc<4;kc++){
        bf16x8 bfr=*(const bf16x8*)(wlds + (nt*16+mrow)*128 + kc*32 + quad*8);
        acc[nt]=__builtin_amdgcn_mfma_f32_16x16x32_bf16(a[kc],bfr,acc[nt],0,0,0);
      }
    }
  }
  #pragma unroll
  for (int nt=0;nt<8;nt++){
    int col=nt*16+mrow;
    float bb=bias[col];
    #pragma unroll
    for (int r=0;r<4;r++){
      int pr=m0+quad*4+r;
      size_t nrow=nf+(size_t)pr;
      float x=acc[nt][r]+bb;
      float v1=b2f(vid1[nrow*128+col]);
      float yv=b2f(yb[nrow*128+col]);
      out[(size_t)frame*2097152 + (size_t)col*16384 + pr]=v1+yv+x;
    }
  }
}

extern "C" void kernel_launch(void* const* d_in, const int* in_sizes, int n_in,
                              void* d_out, int out_size, void* d_ws, size_t ws_size,
                              hipStream_t stream) {
  const float* vid  = (const float*)d_in[0];
  const float* flw  = (const float*)d_in[1];
  const float* g0   = (const float*)d_in[2];
  const float* b0   = (const float*)d_in[3];
  const float* Wq   = (const float*)d_in[4];
  const float* Wk   = (const float*)d_in[5];
  const float* Wv   = (const float*)d_in[6];
  const float* Wo   = (const float*)d_in[7];
  const float* g1   = (const float*)d_in[8];
  const float* b1   = (const float*)d_in[9];
  const float* wr1  = (const float*)d_in[10];
  const float* br1  = (const float*)d_in[11];
  const float* wr2  = (const float*)d_in[12];
  const float* br2  = (const float*)d_in[13];
  float* out = (float*)d_out;

  unsigned short* A  = (unsigned short*)d_ws;
  unsigned short* Bs = A + SLOT_ELEMS;
  unsigned short* Cs = Bs + SLOT_ELEMS;
  bool four = ws_size >= (size_t)4*SLOT_ELEMS*2 + 2*294912;
  unsigned short* D  = four ? (Cs + SLOT_ELEMS) : A;   // q/att/vid1 slot
  unsigned short* wt1 = Cs + SLOT_ELEMS + (four ? SLOT_ELEMS : 0);
  unsigned short* wt2 = wt1 + 147456;

  k_wprep   <<<576, 256, 0, stream>>>(wr1, wr2, wt1, wt2);
  k_ln_nchw <<<256, 256, 0, stream>>>(vid, g0, b0, A);
  k_qkv     <<<1024,256, 0, stream>>>(A, Wq, Wk, Wv, D, Bs, Cs);
  k_attn    <<<2048,256, 0, stream>>>(D, Bs, Cs, flw, D);
  k_wo      <<<1024,256, 0, stream>>>(D, Wo, vid, D);
  k_ln_rows <<<256, 256, 0, stream>>>(D, g1, b1, Bs);
  k_conv_gelu <<<1024,256,0, stream>>>(Bs, wt1, br1, Cs);
  k_conv_final<<<1024,256,0, stream>>>(Cs, wt2, br2, Bs, D, out);
}

// Round 9
// 468.049 us; speedup vs baseline: 1.2101x; 1.0920x over previous
//
#include <hip/hip_runtime.h>

// ---------- bf16 helpers (bit-level, RNE) ----------
__device__ __forceinline__ float bflo(unsigned int u){ return __builtin_bit_cast(float, (unsigned int)(u<<16)); }
__device__ __forceinline__ float bfhi(unsigned int u){ return __builtin_bit_cast(float, (unsigned int)(u & 0xffff0000u)); }
// Raw-hi: treat the full 32-bit word as fp32 (hi bf16 + low-16 mantissa noise <=2^-8).
__device__ __forceinline__ float bfhiraw(unsigned int u){ return __builtin_bit_cast(float, u); }
__device__ __forceinline__ float b2f(unsigned short s){ return __builtin_bit_cast(float, ((unsigned int)s)<<16); }
__device__ __forceinline__ unsigned short f2b(float f){
  unsigned int x = __builtin_bit_cast(unsigned int, f);
  x += 0x7fffu + ((x>>16)&1u);
  return (unsigned short)(x>>16);
}
__device__ __forceinline__ unsigned int packbf(float a, float b){
  return (unsigned int)f2b(a) | ((unsigned int)f2b(b)<<16);
}
__device__ __forceinline__ float dpp_swap1(float s){
  int so = __builtin_amdgcn_mov_dpp(__builtin_bit_cast(int, s), 0xB1, 0xF, 0xF, true); // quad_perm [1,0,3,2]
  return __builtin_bit_cast(float, so);
}

using bf16x8 = __attribute__((ext_vector_type(8))) short;
using f32x4  = __attribute__((ext_vector_type(4))) float;

#define NPOS 65536          // T*H*W
#define SLOT_ELEMS 8388608  // NPOS*128 bf16 elements

// ---------- K0: conv weight fp32 (O,C,3,3) -> bf16 (tap,O,C) ----------
__global__ __launch_bounds__(256) void k_wprep(const float* __restrict__ w1,
                                               const float* __restrict__ w2,
                                               unsigned short* __restrict__ o1,
                                               unsigned short* __restrict__ o2){
  int idx = blockIdx.x*256 + threadIdx.x;
  if (idx >= 147456) return;
  int o = idx / 1152;
  int rem = idx - o*1152;
  int c = rem / 9;
  int tap = rem - c*9;
  int dsti = tap*16384 + o*128 + c;
  o1[dsti] = f2b(w1[idx]);
  o2[dsti] = f2b(w2[idx]);
}

// ---------- K1: LayerNorm over C, fp32 NCHW input -> (N,C) bf16 ----------
__global__ __launch_bounds__(256) void k_ln_nchw(const float* __restrict__ vid,
                                                 const float* __restrict__ g,
                                                 const float* __restrict__ b,
                                                 unsigned short* __restrict__ xf){
  int n = blockIdx.x*256 + threadIdx.x;
  int t = n >> 14, hw = n & 16383;
  const float* base = vid + (size_t)t*2097152 + hw;
  float s=0.f, ss=0.f;
  #pragma unroll 8
  for (int c=0;c<128;c++){ float v=base[(size_t)c*16384]; s+=v; ss+=v*v; }
  float mu  = s*0.0078125f;
  float var = fmaxf(ss*0.0078125f - mu*mu, 0.f);
  float rs  = rsqrtf(var + 1e-6f);
  unsigned int* op = (unsigned int*)(xf + (size_t)n*128);
  #pragma unroll 4
  for (int c=0;c<128;c+=2){
    float v0=(base[(size_t)c*16384]    -mu)*rs*g[c]  +b[c];
    float v1=(base[(size_t)(c+1)*16384]-mu)*rs*g[c+1]+b[c+1];
    op[c>>1]=packbf(v0,v1);
  }
}

// ---------- K5: LayerNorm over C, (N,C) bf16 row-major input ----------
__global__ __launch_bounds__(256) void k_ln_rows(const unsigned short* __restrict__ x,
                                                 const float* __restrict__ g,
                                                 const float* __restrict__ b,
                                                 unsigned short* __restrict__ y){
  int n = blockIdx.x*256 + threadIdx.x;
  const unsigned int* p = (const unsigned int*)(x + (size_t)n*128);
  float s=0.f, ss=0.f;
  #pragma unroll 8
  for (int j=0;j<64;j++){ unsigned int u=p[j]; float v0=bflo(u),v1=bfhi(u); s+=v0+v1; ss+=v0*v0+v1*v1; }
  float mu  = s*0.0078125f;
  float var = fmaxf(ss*0.0078125f - mu*mu, 0.f);
  float rs  = rsqrtf(var + 1e-6f);
  unsigned int* op=(unsigned int*)(y+(size_t)n*128);
  #pragma unroll 8
  for (int j=0;j<64;j++){
    unsigned int u=p[j];
    float v0=(bflo(u)-mu)*rs*g[2*j]  +b[2*j];
    float v1=(bfhi(u)-mu)*rs*g[2*j+1]+b[2*j+1];
    op[j]=packbf(v0,v1);
  }
}

// ---------- K2: QKV projections (unchanged). qf may alias xf ----------
__global__ __launch_bounds__(256) void k_qkv(const unsigned short* xf,
                                             const float* __restrict__ Wq,
                                             const float* __restrict__ Wk,
                                             const float* __restrict__ Wv,
                                             unsigned short* qf,
                                             unsigned short* __restrict__ kfo,
                                             unsigned short* __restrict__ vfo){
  __shared__ unsigned short wlds[16384];
  int wave = threadIdx.x>>6, lane = threadIdx.x&63;
  int m0 = blockIdx.x*64 + wave*16;
  int mrow = lane&15, quad = lane>>4;
  bf16x8 a[4];
  const unsigned short* ap = xf + (size_t)(m0+mrow)*128 + quad*8;
  #pragma unroll
  for (int kc=0;kc<4;kc++) a[kc] = *(const bf16x8*)(ap + kc*32);
  const float* Ws[3] = {Wq, Wk, Wv};
  unsigned short* outs[3] = {qf, kfo, vfo};
  for (int mat=0; mat<3; mat++){
    __syncthreads();
    { const float2* src=(const float2*)Ws[mat]; unsigned int* dst=(unsigned int*)wlds;
      for (int i=threadIdx.x;i<8192;i+=256){ float2 wv=src[i]; dst[i]=packbf(wv.x,wv.y); } }
    __syncthreads();
    unsigned short* out = outs[mat];
    for (int nt=0;nt<8;nt++){
      f32x4 acc = {0.f,0.f,0.f,0.f};
      #pragma unroll
      for (int kc=0;kc<4;kc++){
        bf16x8 bfr = *(const bf16x8*)(wlds + (nt*16+mrow)*128 + kc*32 + quad*8);
        acc = __builtin_amdgcn_mfma_f32_16x16x32_bf16(a[kc], bfr, acc, 0,0,0);
      }
      int col = nt*16+mrow;
      unsigned short* op = out + (size_t)(m0 + quad*4)*128 + col;
      #pragma unroll
      for (int r=0;r<4;r++) op[(size_t)r*128] = f2b(acc[r]);
    }
  }
}

// ---------- K3: attention: channel-split, dw-pipelined; inline addr (no bo[] array) ----------
__global__ __launch_bounds__(256) void k_attn(const unsigned short* qf,
                                              const unsigned short* __restrict__ kf,
                                              const unsigned short* __restrict__ vf,
                                              const float* __restrict__ flw,
                                              unsigned short* attf){
  int xcd = blockIdx.x & 7;
  int j   = blockIdx.x >> 3;      // 0..255
  int t       = j >> 6;           // 0..3
  int r       = j & 63;
  int h_local = r >> 2;           // 0..15
  int wq      = r & 3;            // 0..3
  int h = xcd*16 + h_local;
  int w = wq*32 + (threadIdx.x >> 3);
  int head  = (threadIdx.x >> 1) & 3;
  int cpart = threadIdx.x & 1;
  int hw = (h<<7) + w;
  int n  = (t<<14) + hw;
  float fh = flw[t*32768 + hw];
  float fw = flw[t*32768 + 16384 + hw];
  unsigned coff = head*32 + cpart*16;     // this thread's 16-channel slice
  const uint4* qp = (const uint4*)(qf + (size_t)n*128 + coff);
  float q[16];
  #pragma unroll
  for (int i=0;i<2;i++){
    uint4 qv = qp[i];
    q[8*i+0]=bflo(qv.x); q[8*i+1]=bfhi(qv.x);
    q[8*i+2]=bflo(qv.y); q[8*i+3]=bfhi(qv.y);
    q[8*i+4]=bflo(qv.z); q[8*i+5]=bfhi(qv.z);
    q[8*i+6]=bflo(qv.w); q[8*i+7]=bfhi(qv.w);
  }
  // fold softmax scale into q (exact: scale*(sA+sB) = (scale*sA)+(scale*sB))
  #pragma unroll
  for (int i=0;i<16;i++) q[i] *= 0.17677669529663687f;
  float acc[16];
  #pragma unroll
  for (int i=0;i<16;i++) acc[i]=0.f;
  float l = 0.f;
  #pragma unroll 1
  for (int dt=-1; dt<=1; dt++){
    int ti = t+dt; ti = ti<0?0:(ti>3?3:ti);
    int oh = (int)rintf(fh*(float)dt);   // round-half-even matches jnp.round
    int ow = (int)rintf(fw*(float)dt);
    int hb = h+oh, wb = w+ow;
    #pragma unroll 1
    for (int dh=-3; dh<=3; dh++){
      int hi = hb+dh; hi = hi<0?0:(hi>127?127:hi);
      int rb = (ti<<14)+(hi<<7);
      int wm3 = wb-3;
      // prologue: offset 0
      int w0c = wm3<0?0:(wm3>127?127:wm3);
      unsigned bo0 = ((unsigned)(rb+w0c)<<7) + coff;
      uint4 ka0 = ((const uint4*)(kf + bo0))[0];
      uint4 ka1 = ((const uint4*)(kf + bo0))[1];
      uint4 va0 = ((const uint4*)(vf + bo0))[0];
      uint4 va1 = ((const uint4*)(vf + bo0))[1];
      #pragma unroll
      for (int i=0;i<7;i++){
        uint4 kb0, kb1, vb0, vb1;
        if (i<6){
          int wi = wm3+i+1; wi = wi<0?0:(wi>127?127:wi);
          unsigned bon = ((unsigned)(rb+wi)<<7) + coff;
          kb0 = ((const uint4*)(kf + bon))[0];
          kb1 = ((const uint4*)(kf + bon))[1];
          vb0 = ((const uint4*)(vf + bon))[0];
          vb1 = ((const uint4*)(vf + bon))[1];
        }
        float s = 0.f;
        s += q[0]*bflo(ka0.x) + q[1]*bfhiraw(ka0.x);
        s += q[2]*bflo(ka0.y) + q[3]*bfhiraw(ka0.y);
        s += q[4]*bflo(ka0.z) + q[5]*bfhiraw(ka0.z);
        s += q[6]*bflo(ka0.w) + q[7]*bfhiraw(ka0.w);
        s += q[8]*bflo(ka1.x) + q[9]*bfhiraw(ka1.x);
        s += q[10]*bflo(ka1.y) + q[11]*bfhiraw(ka1.y);
        s += q[12]*bflo(ka1.z) + q[13]*bfhiraw(ka1.z);
        s += q[14]*bflo(ka1.w) + q[15]*bfhiraw(ka1.w);
        s += dpp_swap1(s);               // combine the two channel halves
        float e = __expf(s);
        l += e;
        acc[0]  += e*bflo(va0.x); acc[1]  += e*bfhiraw(va0.x);
        acc[2]  += e*bflo(va0.y); acc[3]  += e*bfhiraw(va0.y);
        acc[4]  += e*bflo(va0.z); acc[5]  += e*bfhiraw(va0.z);
        acc[6]  += e*bflo(va0.w); acc[7]  += e*bfhiraw(va0.w);
        acc[8]  += e*bflo(va1.x); acc[9]  += e*bfhiraw(va1.x);
        acc[10] += e*bflo(va1.y); acc[11] += e*bfhiraw(va1.y);
        acc[12] += e*bflo(va1.z); acc[13] += e*bfhiraw(va1.z);
        acc[14] += e*bflo(va1.w); acc[15] += e*bfhiraw(va1.w);
        ka0=kb0; ka1=kb1; va0=vb0; va1=vb1;
      }
    }
  }
  float inv = 1.f/l;
  unsigned int* op = (unsigned int*)(attf + (size_t)n*128 + coff);
  #pragma unroll
  for (int i=0;i<8;i++) op[i]=packbf(acc[2*i]*inv, acc[2*i+1]*inv);
}

// ---------- K4: Wo projection + residual (unchanged). vid1 may alias attf ----------
__global__ __launch_bounds__(256) void k_wo(const unsigned short* attf,
                                            const float* __restrict__ Wo,
                                            const float* __restrict__ vid,
                                            unsigned short* vid1){
  __shared__ unsigned short wlds[16384];
  int wave = threadIdx.x>>6, lane = threadIdx.x&63;
  int m0 = blockIdx.x*64 + wave*16;
  int mrow = lane&15, quad = lane>>4;
  bf16x8 a[4];
  const unsigned short* ap = attf + (size_t)(m0+mrow)*128 + quad*8;
  #pragma unroll
  for (int kc=0;kc<4;kc++) a[kc] = *(const bf16x8*)(ap + kc*32);
  { const float2* src=(const float2*)Wo; unsigned int* dst=(unsigned int*)wlds;
    for (int i=threadIdx.x;i<8192;i+=256){ float2 wv=src[i]; dst[i]=packbf(wv.x,wv.y); } }
  __syncthreads();
  for (int nt=0;nt<8;nt++){
    f32x4 acc={0.f,0.f,0.f,0.f};
    #pragma unroll
    for (int kc=0;kc<4;kc++){
      bf16x8 bfr = *(const bf16x8*)(wlds + (nt*16+mrow)*128 + kc*32 + quad*8);
      acc = __builtin_amdgcn_mfma_f32_16x16x32_bf16(a[kc], bfr, acc, 0,0,0);
    }
    int col = nt*16+mrow;
    #pragma unroll
    for (int r=0;r<4;r++){
      int nrow = m0 + quad*4 + r;
      int tt = nrow>>14, hww = nrow&16383;
      float resid = vid[(size_t)tt*2097152 + (size_t)col*16384 + hww];
      vid1[(size_t)nrow*128 + col] = f2b(resid + acc[r]);
    }
  }
}

// ---------- K6/K7 shared conv core ----------
// Block = (frame, row h, col-half). M=128 (full row), 64 out channels.
// Per wave: 2 m-tiles of 16 share every B-fragment ds_read (2 MFMA per read).
// Weights for tap t+1 prefetched into 16 VGPRs during tap t compute; 16KB LDS.
#define CONV_PROLOG \
  __shared__ unsigned short wlds[8192]; \
  int wv = threadIdx.x>>6, lane = threadIdx.x&63; \
  int mrow = lane&15, quad = lane>>4; \
  int chalf = blockIdx.x & 1; \
  int h = (blockIdx.x>>1) & 127; \
  int frame = blockIdx.x>>8; \
  size_t nf = (size_t)frame*16384; \
  f32x4 accA[4], accB[4]; \
  _Pragma("unroll") \
  for (int i=0;i<4;i++){ accA[i]=(f32x4){0.f,0.f,0.f,0.f}; accB[i]=(f32x4){0.f,0.f,0.f,0.f}; } \
  { const uint4* sp=(const uint4*)(wtap + chalf*8192); \
    uint4 s0=sp[threadIdx.x], s1=sp[threadIdx.x+256], s2=sp[threadIdx.x+512], s3=sp[threadIdx.x+768]; \
    uint4* d4=(uint4*)wlds; \
    d4[threadIdx.x]=s0; d4[threadIdx.x+256]=s1; d4[threadIdx.x+512]=s2; d4[threadIdx.x+768]=s3; } \
  __syncthreads(); \
  _Pragma("unroll 1") \
  for (int tap=0; tap<9; tap++){ \
    uint4 s0,s1,s2,s3; \
    if (tap<8){ const uint4* sp=(const uint4*)(wtap + (size_t)(tap+1)*16384 + chalf*8192); \
      s0=sp[threadIdx.x]; s1=sp[threadIdx.x+256]; s2=sp[threadIdx.x+512]; s3=sp[threadIdx.x+768]; } \
    int ky=tap/3, kx=tap-3*ky; \
    int h2=h+ky-1; \
    if ((unsigned)h2<128u){ \
      int wA = wv*32 + mrow + kx - 1;            /* [-1,112] */ \
      int wAc = wA < 0 ? 0 : wA; \
      int wB = wA + 16;                          /* [15,128] */ \
      int wBc = wB > 127 ? 127 : wB; \
      const unsigned short* rowp = src + (nf + (size_t)h2*128)*128 + quad*8; \
      const unsigned short* apA = rowp + (size_t)wAc*128; \
      const unsigned short* apB = rowp + (size_t)wBc*128; \
      bf16x8 aA[4], aB[4]; \
      _Pragma("unroll") \
      for (int kc=0;kc<4;kc++){ aA[kc]=*(const bf16x8*)(apA+kc*32); aB[kc]=*(const bf16x8*)(apB+kc*32); } \
      if (kx==0 && wv==0 && mrow==0){ _Pragma("unroll") for (int kc=0;kc<4;kc++) aA[kc]=(bf16x8){0,0,0,0,0,0,0,0}; } \
      if (kx==2 && wv==3 && mrow==15){ _Pragma("unroll") for (int kc=0;kc<4;kc++) aB[kc]=(bf16x8){0,0,0,0,0,0,0,0}; } \
      _Pragma("unroll") \
      for (int nt=0;nt<4;nt++){ \
        _Pragma("unroll") \
        for (int kc=0;kc<4;kc++){ \
          bf16x8 bfr=*(const bf16x8*)(wlds + (nt*16+mrow)*128 + kc*32 + quad*8); \
          accA[nt]=__builtin_amdgcn_mfma_f32_16x16x32_bf16(aA[kc],bfr,accA[nt],0,0,0); \
          accB[nt]=__builtin_amdgcn_mfma_f32_16x16x32_bf16(aB[kc],bfr,accB[nt],0,0,0); \
        } \
      } \
    } \
    __syncthreads(); \
    if (tap<8){ uint4* d4=(uint4*)wlds; \
      d4[threadIdx.x]=s0; d4[threadIdx.x+256]=s1; d4[threadIdx.x+512]=s2; d4[threadIdx.x+768]=s3; \
      __syncthreads(); } \
  }

// ---------- K6: 3x3 conv + bias + tanh-GELU, (N,C) bf16 out ----------
__global__ __launch_bounds__(256) void k_conv_gelu(const unsigned short* __restrict__ src,
                                                   const unsigned short* __restrict__ wtap,
                                                   const float* __restrict__ bias,
                                                   unsigned short* __restrict__ dst){
  CONV_PROLOG
  #pragma unroll
  for (int nt=0;nt<4;nt++){
    int col = chalf*64 + nt*16 + mrow;
    float bb = bias[col];
    #pragma unroll
    for (int r=0;r<4;r++){
      int pA = h*128 + wv*32 + quad*4 + r;
      float xA = accA[nt][r]+bb;
      float zA = 0.7978845608028654f*(xA+0.044715f*xA*xA*xA);
      dst[(nf+(size_t)pA)*128+col] = f2b(xA * __builtin_amdgcn_rcpf(1.f + __expf(-2.f*zA)));
      float xB = accB[nt][r]+bb;
      float zB = 0.7978845608028654f*(xB+0.044715f*xB*xB*xB);
      dst[(nf+(size_t)(pA+16))*128+col] = f2b(xB * __builtin_amdgcn_rcpf(1.f + __expf(-2.f*zB)));
    }
  }
}

// ---------- K7: 3x3 conv + bias + (vid1 + yb + r) -> d_out fp32 NCHW ----------
__global__ __launch_bounds__(256) void k_conv_final(const unsigned short* __restrict__ src,
                                                    const unsigned short* __restrict__ wtap,
                                                    const float* __restrict__ bias,
                                                    const unsigned short* __restrict__ yb,
                                                    const unsigned short* __restrict__ vid1,
                                                    float* __restrict__ out){
  CONV_PROLOG
  #pragma unroll
  for (int nt=0;nt<4;nt++){
    int col = chalf*64 + nt*16 + mrow;
    float bb = bias[col];
    #pragma unroll
    for (int r=0;r<4;r++){
      int pA = h*128 + wv*32 + quad*4 + r;
      size_t rowA = nf+(size_t)pA, rowB = rowA+16;
      float xA = accA[nt][r]+bb;
      out[(size_t)frame*2097152 + (size_t)col*16384 + pA] =
        b2f(vid1[rowA*128+col]) + b2f(yb[rowA*128+col]) + xA;
      float xB = accB[nt][r]+bb;
      out[(size_t)frame*2097152 + (size_t)col*16384 + pA + 16] =
        b2f(vid1[rowB*128+col]) + b2f(yb[rowB*128+col]) + xB;
    }
  }
}

extern "C" void kernel_launch(void* const* d_in, const int* in_sizes, int n_in,
                              void* d_out, int out_size, void* d_ws, size_t ws_size,
                              hipStream_t stream) {
  const float* vid  = (const float*)d_in[0];
  const float* flw  = (const float*)d_in[1];
  const float* g0   = (const float*)d_in[2];
  const float* b0   = (const float*)d_in[3];
  const float* Wq   = (const float*)d_in[4];
  const float* Wk   = (const float*)d_in[5];
  const float* Wv   = (const float*)d_in[6];
  const float* Wo   = (const float*)d_in[7];
  const float* g1   = (const float*)d_in[8];
  const float* b1   = (const float*)d_in[9];
  const float* wr1  = (const float*)d_in[10];
  const float* br1  = (const float*)d_in[11];
  const float* wr2  = (const float*)d_in[12];
  const float* br2  = (const float*)d_in[13];
  float* out = (float*)d_out;

  unsigned short* A  = (unsigned short*)d_ws;
  unsigned short* Bs = A + SLOT_ELEMS;
  unsigned short* Cs = Bs + SLOT_ELEMS;
  bool four = ws_size >= (size_t)4*SLOT_ELEMS*2 + 2*294912;
  unsigned short* D  = four ? (Cs + SLOT_ELEMS) : A;   // q/att/vid1 slot
  unsigned short* wt1 = Cs + SLOT_ELEMS + (four ? SLOT_ELEMS : 0);
  unsigned short* wt2 = wt1 + 147456;

  k_wprep   <<<576, 256, 0, stream>>>(wr1, wr2, wt1, wt2);
  k_ln_nchw <<<256, 256, 0, stream>>>(vid, g0, b0, A);
  k_qkv     <<<1024,256, 0, stream>>>(A, Wq, Wk, Wv, D, Bs, Cs);
  k_attn    <<<2048,256, 0, stream>>>(D, Bs, Cs, flw, D);
  k_wo      <<<1024,256, 0, stream>>>(D, Wo, vid, D);
  k_ln_rows <<<256, 256, 0, stream>>>(D, g1, b1, Bs);
  k_conv_gelu <<<1024,256,0, stream>>>(Bs, wt1, br1, Cs);
  k_conv_final<<<1024,256,0, stream>>>(Cs, wt2, br2, Bs, D, out);
}